// Round 8
// baseline (832.099 us; speedup 1.0000x reference)
//
#include <hip/hip_runtime.h>

#define IN_DIM 512
#define HID 64
#define OUT_DIM 5

typedef __attribute__((ext_vector_type(4))) float f32x4;
typedef __attribute__((ext_vector_type(4))) int   i32x4;

// ---------------- bf16 helpers (RNE) ----------------

__device__ __forceinline__ unsigned short f2bf(float f) {
    unsigned u = __float_as_uint(f);
    u += 0x7FFF + ((u >> 16) & 1);
    return (unsigned short)(u >> 16);
}
__device__ __forceinline__ float bf2f(unsigned short b) {
    return __uint_as_float(((unsigned)b) << 16);
}

// edge record unpack: int2 loaded as 64-bit (low = src, high = weight bits)
__device__ __forceinline__ int ed_src(long long v) { return (int)(v & 0xffffffffLL); }
__device__ __forceinline__ float ed_w(long long v) { return __int_as_float((int)(v >> 32)); }

// ---------------- init: packed deg/count accumulator = 0 ----------------

__global__ void k_init(unsigned long long* __restrict__ packed, int n) {
    int i = blockIdx.x * blockDim.x + threadIdx.x;
    if (i < n) packed[i] = 0ULL;
}

// ---------------- fused GEMM1 + hist ----------------
// GEMM1 (x @ W1) is independent of the CSR build; hist is bound by the fabric
// atomic transaction rate (~22 G atomics/s — insensitive to concurrency (r4
// probe) AND to per-line spreading (r7 copy-split probe) -> structural).
// Block-split fusion hides GEMM1 under the atomic wait. NT hints on all
// single-use streams (x, dst, ew, rank) keep L2 for reusable data.
// packed[d]: bits[63:44]=count, [43:0]=sum(ew) 12.32 fixed pt; atomic return
// = edge's rank within its dst bucket.

__launch_bounds__(256)
__global__ void k_gemm1_hist(const float* __restrict__ A, const float* __restrict__ W,
                             float* __restrict__ out, unsigned short* __restrict__ outb, int M,
                             const int* __restrict__ dst, const float* __restrict__ ew,
                             unsigned long long* __restrict__ packed, int* __restrict__ rank,
                             int nE, int gemmBlocks) {
    if ((int)blockIdx.x < gemmBlocks) {
        constexpr int K_ = IN_DIM;
        constexpr int BK = 16;
        __shared__ float As[BK][68];
        __shared__ float Ws[BK][64];

        const int t  = threadIdx.x;
        const int tx = t & 15;
        const int ty = t >> 4;
        const int row0 = blockIdx.x * 64;

        const int lr = t >> 2;
        const int lk = (t & 3) * 4;

        float acc[4][4] = {};

        for (int k0 = 0; k0 < K_; k0 += BK) {
            f32x4 av = {0.f, 0.f, 0.f, 0.f};
            int ar = row0 + lr;
            if (ar < M)
                av = __builtin_nontemporal_load((const f32x4*)&A[(long long)ar * K_ + k0 + lk]);
            As[lk + 0][lr] = av[0];
            As[lk + 1][lr] = av[1];
            As[lk + 2][lr] = av[2];
            As[lk + 3][lr] = av[3];

            *(float4*)&Ws[t >> 4][(t & 15) * 4] =
                *(const float4*)&W[(long long)(k0 + (t >> 4)) * 64 + (t & 15) * 4];

            __syncthreads();

#pragma unroll
            for (int kk = 0; kk < BK; ++kk) {
                float4 a4 = *(const float4*)&As[kk][ty * 4];
                float4 b4 = *(const float4*)&Ws[kk][tx * 4];
                float a[4] = {a4.x, a4.y, a4.z, a4.w};
                float b[4] = {b4.x, b4.y, b4.z, b4.w};
#pragma unroll
                for (int i = 0; i < 4; ++i)
#pragma unroll
                    for (int j = 0; j < 4; ++j)
                        acc[i][j] = fmaf(a[i], b[j], acc[i][j]);
            }
            __syncthreads();
        }

#pragma unroll
        for (int i = 0; i < 4; ++i) {
            int r = row0 + ty * 4 + i;
            if (r < M) {
                *(float4*)&out[(long long)r * 64 + tx * 4] =
                    make_float4(acc[i][0], acc[i][1], acc[i][2], acc[i][3]);
                ushort4 hv;
                hv.x = f2bf(acc[i][0]);
                hv.y = f2bf(acc[i][1]);
                hv.z = f2bf(acc[i][2]);
                hv.w = f2bf(acc[i][3]);
                *(ushort4*)&outb[(long long)r * 64 + tx * 4] = hv;
            }
        }
    } else {
        int base = ((blockIdx.x - gemmBlocks) * 256 + threadIdx.x) * 4;
        if (base + 3 < nE) {
            i32x4 d4 = __builtin_nontemporal_load((const i32x4*)&dst[base]);
            f32x4 w4 = __builtin_nontemporal_load((const f32x4*)&ew[base]);
            unsigned long long f0 = (unsigned long long)(w4[0] * 4294967296.0);
            unsigned long long f1 = (unsigned long long)(w4[1] * 4294967296.0);
            unsigned long long f2 = (unsigned long long)(w4[2] * 4294967296.0);
            unsigned long long f3 = (unsigned long long)(w4[3] * 4294967296.0);
            unsigned long long o0 = atomicAdd(&packed[d4[0]], (1ULL << 44) | f0);
            unsigned long long o1 = atomicAdd(&packed[d4[1]], (1ULL << 44) | f1);
            unsigned long long o2 = atomicAdd(&packed[d4[2]], (1ULL << 44) | f2);
            unsigned long long o3 = atomicAdd(&packed[d4[3]], (1ULL << 44) | f3);
            i32x4 r4;
            r4[0] = (int)(o0 >> 44);
            r4[1] = (int)(o1 >> 44);
            r4[2] = (int)(o2 >> 44);
            r4[3] = (int)(o3 >> 44);
            __builtin_nontemporal_store(r4, (i32x4*)&rank[base]);
        } else {
            for (int e = base; e < nE; ++e) {
                int d = dst[e];
                unsigned long long fx = (unsigned long long)(ew[e] * 4294967296.0);
                unsigned long long old = atomicAdd(&packed[d], (1ULL << 44) | fx);
                rank[e] = (int)(old >> 44);
            }
        }
    }
}

// ---------------- scan1 + dinv fused: reads packed directly ----------------
// dinv = rsqrt(1 + sum_ew); cnt extracted inline for the block-level scan.

__global__ void k_scan1d(const unsigned long long* __restrict__ packed,
                         float* __restrict__ dinv, int* __restrict__ rowptr,
                         int* __restrict__ bsum, int n) {
    __shared__ int sdata[256];
    int t = threadIdx.x, b = blockIdx.x;
    int base = b * 1024 + t * 4;
    int v[4], s = 0;
#pragma unroll
    for (int k = 0; k < 4; ++k) {
        int i = base + k;
        int c = 0;
        if (i < n) {
            unsigned long long p = packed[i];
            c = (int)(p >> 44);
            double ewsum = (double)(p & ((1ULL << 44) - 1)) * (1.0 / 4294967296.0);
            dinv[i] = rsqrtf(1.0f + (float)ewsum);
        }
        v[k] = c;
        s += c;
    }
    sdata[t] = s;
    __syncthreads();
    int x = s;
    for (int off = 1; off < 256; off <<= 1) {
        int y = (t >= off) ? sdata[t - off] : 0;
        __syncthreads();
        x += y;
        sdata[t] = x;
        __syncthreads();
    }
    int run = x - s;
    if (t == 255) bsum[b] = x;
#pragma unroll
    for (int k = 0; k < 4; ++k) { int i = base + k; if (i < n) rowptr[i] = run; run += v[k]; }
}

__global__ void k_scan2(int* __restrict__ bsum, int nb) {
    __shared__ int sdata[256];
    int t = threadIdx.x;
    int s = (t < nb) ? bsum[t] : 0;
    sdata[t] = s;
    __syncthreads();
    int x = s;
    for (int off = 1; off < 256; off <<= 1) {
        int y = (t >= off) ? sdata[t - off] : 0;
        __syncthreads();
        x += y;
        sdata[t] = x;
        __syncthreads();
    }
    if (t < nb) bsum[t] = x - s;
}

__global__ void k_scan3(int* __restrict__ rowptr, const int* __restrict__ bsum, int n, int E) {
    int i = blockIdx.x * blockDim.x + threadIdx.x;
    if (i < n) rowptr[i] += bsum[i >> 10];
    else if (i == n) rowptr[n] = E;
}

// ---------------- reorder: NO atomics — pos = rowptr[dst] + rank ----------------
// NT loads on the 51 MB of single-use streams so the scattered edges[] writes
// (25.6 MB = 3.2 MB/XCD, fits L2) can write-combine in L2: each 128B line
// receives ~16 partial 8B writes; keeping those lines resident between writes
// removes the write-allocate fetch/writeback churn.

__global__ void k_reorder(const int* __restrict__ src, const int* __restrict__ dst,
                          const float* __restrict__ ew, const float* __restrict__ dinv,
                          const int* __restrict__ rowptr, const int* __restrict__ rank,
                          int2* __restrict__ edges, int nE) {
    int e = blockIdx.x * blockDim.x + threadIdx.x;
    if (e < nE) {
        int   s  = __builtin_nontemporal_load(&src[e]);
        int   d  = __builtin_nontemporal_load(&dst[e]);
        float wv = __builtin_nontemporal_load(&ew[e]);
        int   rk = __builtin_nontemporal_load(&rank[e]);
        float w = dinv[s] * wv * dinv[d];
        int pos = rowptr[d] + rk;
        edges[pos] = make_int2(s, __float_as_int(w));
    }
}

// ---------------- aggregate: out[n,:] = dinv[n]^2*h[n,:] + sum_e w_e * hb[src_e,:] ----
// one wave per node, lane = feature. hb row = 64*bf16 = 128 B = one cache line,
// fully consumed per wave-gather. NT on the edge/h streams + out store protects
// L2 capacity for the hb gather table (reused 32x/line per pass).

__launch_bounds__(256)
__global__ void k_aggregate(const float* __restrict__ h, const unsigned short* __restrict__ hb,
                            const float* __restrict__ dinv,
                            const int2* __restrict__ edges, const int* __restrict__ rowptr,
                            float* __restrict__ out, int N) {
    int n = (blockIdx.x * 256 + threadIdx.x) >> 6;
    int lane = threadIdx.x & 63;
    if (n >= N) return;

    const long long* __restrict__ edg = (const long long*)edges;

    float dn = dinv[n];
    float acc = dn * dn * __builtin_nontemporal_load(&h[(size_t)n * HID + lane]);

    int beg = rowptr[n], end = rowptr[n + 1];
    int j = beg;
    for (; j + 7 < end; j += 8) {
        long long p0 = __builtin_nontemporal_load(&edg[j]);
        long long p1 = __builtin_nontemporal_load(&edg[j + 1]);
        long long p2 = __builtin_nontemporal_load(&edg[j + 2]);
        long long p3 = __builtin_nontemporal_load(&edg[j + 3]);
        long long p4 = __builtin_nontemporal_load(&edg[j + 4]);
        long long p5 = __builtin_nontemporal_load(&edg[j + 5]);
        long long p6 = __builtin_nontemporal_load(&edg[j + 6]);
        long long p7 = __builtin_nontemporal_load(&edg[j + 7]);
        float h0 = bf2f(hb[(size_t)ed_src(p0) * HID + lane]);
        float h1 = bf2f(hb[(size_t)ed_src(p1) * HID + lane]);
        float h2 = bf2f(hb[(size_t)ed_src(p2) * HID + lane]);
        float h3 = bf2f(hb[(size_t)ed_src(p3) * HID + lane]);
        float h4 = bf2f(hb[(size_t)ed_src(p4) * HID + lane]);
        float h5 = bf2f(hb[(size_t)ed_src(p5) * HID + lane]);
        float h6 = bf2f(hb[(size_t)ed_src(p6) * HID + lane]);
        float h7 = bf2f(hb[(size_t)ed_src(p7) * HID + lane]);
        acc = fmaf(ed_w(p0), h0, acc);
        acc = fmaf(ed_w(p1), h1, acc);
        acc = fmaf(ed_w(p2), h2, acc);
        acc = fmaf(ed_w(p3), h3, acc);
        acc = fmaf(ed_w(p4), h4, acc);
        acc = fmaf(ed_w(p5), h5, acc);
        acc = fmaf(ed_w(p6), h6, acc);
        acc = fmaf(ed_w(p7), h7, acc);
    }
    for (; j < end; ++j) {
        long long p = __builtin_nontemporal_load(&edg[j]);
        acc = fmaf(ed_w(p), bf2f(hb[(size_t)ed_src(p) * HID + lane]), acc);
    }
    __builtin_nontemporal_store(acc, &out[(size_t)n * HID + lane]);
}

// ---------------- tiled GEMM: out[M,64] = act(A[M,K]) @ W[K,64]; also bf16 copy ----------------

template <int K_, bool RELU_BIAS>
__launch_bounds__(256)
__global__ void k_gemm_n64(const float* __restrict__ A, const float* __restrict__ W,
                           const float* __restrict__ bias, float* __restrict__ out,
                           unsigned short* __restrict__ outb, int M) {
    constexpr int BK = 16;
    __shared__ float As[BK][68];
    __shared__ float Ws[BK][64];

    const int t  = threadIdx.x;
    const int tx = t & 15;
    const int ty = t >> 4;
    const int row0 = blockIdx.x * 64;

    const int lr = t >> 2;
    const int lk = (t & 3) * 4;

    float acc[4][4] = {};

    for (int k0 = 0; k0 < K_; k0 += BK) {
        float4 av = make_float4(0.f, 0.f, 0.f, 0.f);
        int ar = row0 + lr;
        if (ar < M) {
            av = *(const float4*)&A[(long long)ar * K_ + k0 + lk];
            if (RELU_BIAS) {
                const float4 bv = *(const float4*)&bias[k0 + lk];
                av.x = fmaxf(av.x + bv.x, 0.f);
                av.y = fmaxf(av.y + bv.y, 0.f);
                av.z = fmaxf(av.z + bv.z, 0.f);
                av.w = fmaxf(av.w + bv.w, 0.f);
            }
        }
        As[lk + 0][lr] = av.x;
        As[lk + 1][lr] = av.y;
        As[lk + 2][lr] = av.z;
        As[lk + 3][lr] = av.w;

        *(float4*)&Ws[t >> 4][(t & 15) * 4] =
            *(const float4*)&W[(long long)(k0 + (t >> 4)) * 64 + (t & 15) * 4];

        __syncthreads();

#pragma unroll
        for (int kk = 0; kk < BK; ++kk) {
            float4 a4 = *(const float4*)&As[kk][ty * 4];
            float4 b4 = *(const float4*)&Ws[kk][tx * 4];
            float a[4] = {a4.x, a4.y, a4.z, a4.w};
            float b[4] = {b4.x, b4.y, b4.z, b4.w};
#pragma unroll
            for (int i = 0; i < 4; ++i)
#pragma unroll
                for (int j = 0; j < 4; ++j)
                    acc[i][j] = fmaf(a[i], b[j], acc[i][j]);
        }
        __syncthreads();
    }

#pragma unroll
    for (int i = 0; i < 4; ++i) {
        int r = row0 + ty * 4 + i;
        if (r < M) {
            *(float4*)&out[(long long)r * 64 + tx * 4] =
                make_float4(acc[i][0], acc[i][1], acc[i][2], acc[i][3]);
            ushort4 hv;
            hv.x = f2bf(acc[i][0]);
            hv.y = f2bf(acc[i][1]);
            hv.z = f2bf(acc[i][2]);
            hv.w = f2bf(acc[i][3]);
            *(ushort4*)&outb[(long long)r * 64 + tx * 4] = hv;
        }
    }
}

// ---------------- final: out[n,:5] = relu(agg[n,:]+b2) @ Wfc + bfc ----------------

__launch_bounds__(256)
__global__ void k_final(const float* __restrict__ agg, const float* __restrict__ b2,
                        const float* __restrict__ Wfc, const float* __restrict__ bfc,
                        float* __restrict__ out, int N) {
    __shared__ float Wsf[HID * OUT_DIM];
    __shared__ float bs[HID];
    int t = threadIdx.x;
    for (int i = t; i < HID * OUT_DIM; i += 256) Wsf[i] = Wfc[i];
    if (t < HID) bs[t] = b2[t];
    __syncthreads();

    int n = blockIdx.x * blockDim.x + t;
    if (n >= N) return;

    float acc[OUT_DIM];
#pragma unroll
    for (int o = 0; o < OUT_DIM; ++o) acc[o] = bfc[o];

    const float4* ag = (const float4*)&agg[(long long)n * HID];
#pragma unroll
    for (int k4 = 0; k4 < HID / 4; ++k4) {
        float4 v4 = ag[k4];
        float v[4] = {v4.x, v4.y, v4.z, v4.w};
#pragma unroll
        for (int j = 0; j < 4; ++j) {
            int k = k4 * 4 + j;
            float f = fmaxf(v[j] + bs[k], 0.f);
#pragma unroll
            for (int o = 0; o < OUT_DIM; ++o)
                acc[o] = fmaf(f, Wsf[k * OUT_DIM + o], acc[o]);
        }
    }
#pragma unroll
    for (int o = 0; o < OUT_DIM; ++o) out[(long long)n * OUT_DIM + o] = acc[o];
}

// ---------------- host launch ----------------

static inline size_t align_up(size_t x, size_t a) { return (x + a - 1) & ~(a - 1); }

extern "C" void kernel_launch(void* const* d_in, const int* in_sizes, int n_in,
                              void* d_out, int out_size, void* d_ws, size_t ws_size,
                              hipStream_t stream) {
    const float* x   = (const float*)d_in[0];
    const int*   ei  = (const int*)d_in[1];   // [2][E] int32
    const float* ew  = (const float*)d_in[2];
    const float* W1  = (const float*)d_in[3];
    const float* b1  = (const float*)d_in[4];
    const float* W2  = (const float*)d_in[5];
    const float* b2  = (const float*)d_in[6];
    const float* Wfc = (const float*)d_in[7];
    const float* bfc = (const float*)d_in[8];
    float* out = (float*)d_out;

    const int E = in_sizes[2];              // 3200000
    const int N = in_sizes[0] / IN_DIM;     // 100000
    const int* src = ei;
    const int* dst = ei + E;

    // workspace carve. Aliasing: rank lives in bufB — rank is read last by
    // k_reorder; bufB is first written by k_aggregate (strictly later, same
    // stream). hb is a real buffer (GEMM1 writes it concurrently with hist
    // writing rank).
    char* p = (char*)d_ws;
    unsigned long long* packed = (unsigned long long*)p; p += align_up((size_t)N * 8, 256);
    float* dinv   = (float*)p;  p += align_up((size_t)N * 4, 256);
    int*   rowptr = (int*)p;    p += align_up((size_t)(N + 1) * 4, 256);
    int*   bsum   = (int*)p;    p += align_up((size_t)256 * 4, 256);
    unsigned short* hb = (unsigned short*)p; p += align_up((size_t)N * HID * 2, 256); // 12.8 MB
    int2*  edges  = (int2*)p;   p += align_up((size_t)E * 8, 256);   // 25.6 MB
    float* bufA   = (float*)p;  p += align_up((size_t)N * HID * 4, 256);
    float* bufB   = (float*)p;  p += align_up((size_t)N * HID * 4, 256);
    int*   rank   = (int*)bufB;  // E*4 = 12.8 MB <= bufB's 25.6 MB
    (void)ws_size; (void)n_in; (void)out_size;

    const int BS = 256;
    dim3 blk(BS);
    int gN  = (N + BS - 1) / BS;
    int gN1 = (N + 1 + BS - 1) / BS;
    int gE  = (E + BS - 1) / BS;
    int gE4 = (E + BS * 4 - 1) / (BS * 4);
    int gM  = (N + 63) / 64;
    int nb  = (N + 1023) / 1024;
    int gAg = (N + 3) / 4;

    // CSR build overlapped with GEMM1 (independent inputs)
    k_init<<<gN, blk, 0, stream>>>(packed, N);
    k_gemm1_hist<<<gM + gE4, blk, 0, stream>>>(x, W1, bufA, hb, N,
                                               dst, ew, packed, rank, E, gM);
    k_scan1d<<<nb, blk, 0, stream>>>(packed, dinv, rowptr, bsum, N);
    k_scan2<<<1, blk, 0, stream>>>(bsum, nb);
    k_scan3<<<gN1, blk, 0, stream>>>(rowptr, bsum, N, E);
    k_reorder<<<gE, blk, 0, stream>>>(src, dst, ew, dinv, rowptr, rank, edges, E);

    // layer 1 aggregate (writes bufB — rank dead from here on)
    k_aggregate<<<gAg, blk, 0, stream>>>(bufA, hb, dinv, edges, rowptr, bufB, N);

    // layer 2
    k_gemm_n64<HID, true><<<gM, blk, 0, stream>>>(bufB, W2, b1, bufA, hb, N);
    k_aggregate<<<gAg, blk, 0, stream>>>(bufA, hb, dinv, edges, rowptr, bufB, N);

    // final FC
    k_final<<<gN, blk, 0, stream>>>(bufB, b2, Wfc, bfc, out, N);
}

// Round 10
// 796.967 us; speedup vs baseline: 1.0441x; 1.0441x over previous
//
#include <hip/hip_runtime.h>

#define IN_DIM 512
#define HID 64
#define OUT_DIM 5

// ---------------- bf16 helpers (RNE) ----------------

__device__ __forceinline__ unsigned short f2bf(float f) {
    unsigned u = __float_as_uint(f);
    u += 0x7FFF + ((u >> 16) & 1);
    return (unsigned short)(u >> 16);
}
__device__ __forceinline__ float bf2f(unsigned short b) {
    return __uint_as_float(((unsigned)b) << 16);
}

// ---------------- init: packed deg/count accumulator = 0 ----------------

__global__ void k_init(unsigned long long* __restrict__ packed, int n) {
    int i = blockIdx.x * blockDim.x + threadIdx.x;
    if (i < n) packed[i] = 0ULL;
}

// ---------------- fused GEMM1 + hist ----------------
// GEMM1 (x @ W1) is independent of the CSR build; hist is bound by the fabric
// atomic transaction rate (~22 G atomics/s — insensitive to concurrency (r4),
// per-line spreading (r7), and NT hints (r8) -> structural). Block-split
// fusion hides GEMM1 under the atomic wait. NO NT hints (r8: +84 us, FETCH
// 114->149 MB — caches were already handling the streams).
// packed[d]: bits[63:44]=count, [43:0]=sum(ew) 12.32 fixed pt; atomic return
// = edge's rank within its dst bucket.

__launch_bounds__(256)
__global__ void k_gemm1_hist(const float* __restrict__ A, const float* __restrict__ W,
                             float* __restrict__ out, unsigned short* __restrict__ outb, int M,
                             const int* __restrict__ dst, const float* __restrict__ ew,
                             unsigned long long* __restrict__ packed, int* __restrict__ rank,
                             int nE, int gemmBlocks) {
    if ((int)blockIdx.x < gemmBlocks) {
        constexpr int K_ = IN_DIM;
        constexpr int BK = 16;
        __shared__ float As[BK][68];
        __shared__ float Ws[BK][64];

        const int t  = threadIdx.x;
        const int tx = t & 15;
        const int ty = t >> 4;
        const int row0 = blockIdx.x * 64;

        const int lr = t >> 2;
        const int lk = (t & 3) * 4;

        float acc[4][4] = {};

        for (int k0 = 0; k0 < K_; k0 += BK) {
            float4 av = make_float4(0.f, 0.f, 0.f, 0.f);
            int ar = row0 + lr;
            if (ar < M) av = *(const float4*)&A[(long long)ar * K_ + k0 + lk];
            As[lk + 0][lr] = av.x;
            As[lk + 1][lr] = av.y;
            As[lk + 2][lr] = av.z;
            As[lk + 3][lr] = av.w;

            *(float4*)&Ws[t >> 4][(t & 15) * 4] =
                *(const float4*)&W[(long long)(k0 + (t >> 4)) * 64 + (t & 15) * 4];

            __syncthreads();

#pragma unroll
            for (int kk = 0; kk < BK; ++kk) {
                float4 a4 = *(const float4*)&As[kk][ty * 4];
                float4 b4 = *(const float4*)&Ws[kk][tx * 4];
                float a[4] = {a4.x, a4.y, a4.z, a4.w};
                float b[4] = {b4.x, b4.y, b4.z, b4.w};
#pragma unroll
                for (int i = 0; i < 4; ++i)
#pragma unroll
                    for (int j = 0; j < 4; ++j)
                        acc[i][j] = fmaf(a[i], b[j], acc[i][j]);
            }
            __syncthreads();
        }

#pragma unroll
        for (int i = 0; i < 4; ++i) {
            int r = row0 + ty * 4 + i;
            if (r < M) {
                *(float4*)&out[(long long)r * 64 + tx * 4] =
                    make_float4(acc[i][0], acc[i][1], acc[i][2], acc[i][3]);
                ushort4 hv;
                hv.x = f2bf(acc[i][0]);
                hv.y = f2bf(acc[i][1]);
                hv.z = f2bf(acc[i][2]);
                hv.w = f2bf(acc[i][3]);
                *(ushort4*)&outb[(long long)r * 64 + tx * 4] = hv;
            }
        }
    } else {
        int base = ((blockIdx.x - gemmBlocks) * 256 + threadIdx.x) * 4;
        if (base + 3 < nE) {
            int4   d4 = *(const int4*)&dst[base];
            float4 w4 = *(const float4*)&ew[base];
            unsigned long long f0 = (unsigned long long)(w4.x * 4294967296.0);
            unsigned long long f1 = (unsigned long long)(w4.y * 4294967296.0);
            unsigned long long f2 = (unsigned long long)(w4.z * 4294967296.0);
            unsigned long long f3 = (unsigned long long)(w4.w * 4294967296.0);
            unsigned long long o0 = atomicAdd(&packed[d4.x], (1ULL << 44) | f0);
            unsigned long long o1 = atomicAdd(&packed[d4.y], (1ULL << 44) | f1);
            unsigned long long o2 = atomicAdd(&packed[d4.z], (1ULL << 44) | f2);
            unsigned long long o3 = atomicAdd(&packed[d4.w], (1ULL << 44) | f3);
            int4 r4;
            r4.x = (int)(o0 >> 44);
            r4.y = (int)(o1 >> 44);
            r4.z = (int)(o2 >> 44);
            r4.w = (int)(o3 >> 44);
            *(int4*)&rank[base] = r4;
        } else {
            for (int e = base; e < nE; ++e) {
                int d = dst[e];
                unsigned long long fx = (unsigned long long)(ew[e] * 4294967296.0);
                unsigned long long old = atomicAdd(&packed[d], (1ULL << 44) | fx);
                rank[e] = (int)(old >> 44);
            }
        }
    }
}

// ---------------- scan1 + dinv fused: reads packed directly ----------------

__global__ void k_scan1d(const unsigned long long* __restrict__ packed,
                         float* __restrict__ dinv, int* __restrict__ rowptr,
                         int* __restrict__ bsum, int n) {
    __shared__ int sdata[256];
    int t = threadIdx.x, b = blockIdx.x;
    int base = b * 1024 + t * 4;
    int v[4], s = 0;
#pragma unroll
    for (int k = 0; k < 4; ++k) {
        int i = base + k;
        int c = 0;
        if (i < n) {
            unsigned long long p = packed[i];
            c = (int)(p >> 44);
            double ewsum = (double)(p & ((1ULL << 44) - 1)) * (1.0 / 4294967296.0);
            dinv[i] = rsqrtf(1.0f + (float)ewsum);
        }
        v[k] = c;
        s += c;
    }
    sdata[t] = s;
    __syncthreads();
    int x = s;
    for (int off = 1; off < 256; off <<= 1) {
        int y = (t >= off) ? sdata[t - off] : 0;
        __syncthreads();
        x += y;
        sdata[t] = x;
        __syncthreads();
    }
    int run = x - s;
    if (t == 255) bsum[b] = x;
#pragma unroll
    for (int k = 0; k < 4; ++k) { int i = base + k; if (i < n) rowptr[i] = run; run += v[k]; }
}

__global__ void k_scan2(int* __restrict__ bsum, int nb) {
    __shared__ int sdata[256];
    int t = threadIdx.x;
    int s = (t < nb) ? bsum[t] : 0;
    sdata[t] = s;
    __syncthreads();
    int x = s;
    for (int off = 1; off < 256; off <<= 1) {
        int y = (t >= off) ? sdata[t - off] : 0;
        __syncthreads();
        x += y;
        sdata[t] = x;
        __syncthreads();
    }
    if (t < nb) bsum[t] = x - s;
}

__global__ void k_scan3(int* __restrict__ rowptr, const int* __restrict__ bsum, int n, int E) {
    int i = blockIdx.x * blockDim.x + threadIdx.x;
    if (i < n) rowptr[i] += bsum[i >> 10];
    else if (i == n) rowptr[n] = E;
}

// ---------------- reorder: NO atomics — pos = rowptr[dst] + rank ----------------

__global__ void k_reorder(const int* __restrict__ src, const int* __restrict__ dst,
                          const float* __restrict__ ew, const float* __restrict__ dinv,
                          const int* __restrict__ rowptr, const int* __restrict__ rank,
                          int2* __restrict__ edges, int nE) {
    int e = blockIdx.x * blockDim.x + threadIdx.x;
    if (e < nE) {
        int s = src[e];
        int d = dst[e];
        float w = dinv[s] * ew[e] * dinv[d];
        int pos = rowptr[d] + rank[e];
        edges[pos] = make_int2(s, __float_as_int(w));
    }
}

// ---------------- fused aggregate1 + GEMM2 ----------------
// Wave per node: aggregate loop leaves the node's 64-dim row in registers
// (lane = feature). Then f = relu(acc + b1[lane]) and the 64x64 GEMM runs
// in-wave: o_j = sum_k shfl(f,k) * W2s[k][j] (W2 in LDS, conflict-free row
// reads). Kills the separate gemm2 kernel + the bufB write->read round-trip.
// Writes h2 fp32 (bufB, self-term for layer 2) + hb2 bf16 (gather table).
// hb2 != hb1: gather reads layer-1 hb1 while hb2 is written (wave-own rows).

__launch_bounds__(256)
__global__ void k_agg_gemm2(const float* __restrict__ h, const unsigned short* __restrict__ hb,
                            const float* __restrict__ dinv,
                            const int2* __restrict__ edges, const int* __restrict__ rowptr,
                            const float* __restrict__ b1, const float* __restrict__ W2,
                            float* __restrict__ h2, unsigned short* __restrict__ hb2, int N) {
    __shared__ float W2s[HID][HID];   // 16 KB
    __shared__ float b1s[HID];
    const int t = threadIdx.x;
    for (int i = t * 4; i < HID * HID; i += 256 * 4)
        *(float4*)&W2s[0][i] = *(const float4*)&W2[i];
    if (t < HID) b1s[t] = b1[t];
    __syncthreads();

    int n = (blockIdx.x * 256 + t) >> 6;
    int lane = t & 63;
    if (n >= N) return;

    float dn = dinv[n];
    float acc = dn * dn * h[(size_t)n * HID + lane];

    int beg = rowptr[n], end = rowptr[n + 1];
    int j = beg;
    for (; j + 7 < end; j += 8) {
        int2 p0 = edges[j];
        int2 p1 = edges[j + 1];
        int2 p2 = edges[j + 2];
        int2 p3 = edges[j + 3];
        int2 p4 = edges[j + 4];
        int2 p5 = edges[j + 5];
        int2 p6 = edges[j + 6];
        int2 p7 = edges[j + 7];
        float h0 = bf2f(hb[(size_t)p0.x * HID + lane]);
        float h1 = bf2f(hb[(size_t)p1.x * HID + lane]);
        float h2v = bf2f(hb[(size_t)p2.x * HID + lane]);
        float h3 = bf2f(hb[(size_t)p3.x * HID + lane]);
        float h4 = bf2f(hb[(size_t)p4.x * HID + lane]);
        float h5 = bf2f(hb[(size_t)p5.x * HID + lane]);
        float h6 = bf2f(hb[(size_t)p6.x * HID + lane]);
        float h7 = bf2f(hb[(size_t)p7.x * HID + lane]);
        acc = fmaf(__int_as_float(p0.y), h0, acc);
        acc = fmaf(__int_as_float(p1.y), h1, acc);
        acc = fmaf(__int_as_float(p2.y), h2v, acc);
        acc = fmaf(__int_as_float(p3.y), h3, acc);
        acc = fmaf(__int_as_float(p4.y), h4, acc);
        acc = fmaf(__int_as_float(p5.y), h5, acc);
        acc = fmaf(__int_as_float(p6.y), h6, acc);
        acc = fmaf(__int_as_float(p7.y), h7, acc);
    }
    for (; j < end; ++j) {
        int2 p = edges[j];
        acc = fmaf(__int_as_float(p.y), bf2f(hb[(size_t)p.x * HID + lane]), acc);
    }

    // layer-1 epilogue + in-wave 64x64 GEMM
    float f = fmaxf(acc + b1s[lane], 0.f);
    float o = 0.f;
#pragma unroll
    for (int k = 0; k < HID; ++k)
        o = fmaf(__shfl(f, k, 64), W2s[k][lane], o);

    h2[(size_t)n * HID + lane] = o;
    hb2[(size_t)n * HID + lane] = f2bf(o);
}

// ---------------- fused aggregate2 + final FC ----------------
// Wave per node: aggregate layer 2, then f = relu(acc + b2[lane]) and
// out[n][o] = butterfly_sum(f * Wfc[lane][o]) + bfc[o]. Kills k_final + the
// bufB round-trip.

__launch_bounds__(256)
__global__ void k_agg_final(const float* __restrict__ h, const unsigned short* __restrict__ hb,
                            const float* __restrict__ dinv,
                            const int2* __restrict__ edges, const int* __restrict__ rowptr,
                            const float* __restrict__ b2, const float* __restrict__ Wfc,
                            const float* __restrict__ bfc, float* __restrict__ out, int N) {
    __shared__ float Wfs[HID * OUT_DIM];
    __shared__ float b2s[HID];
    __shared__ float bfcs[OUT_DIM];
    const int t = threadIdx.x;
    for (int i = t; i < HID * OUT_DIM; i += 256) Wfs[i] = Wfc[i];
    if (t < HID) b2s[t] = b2[t];
    if (t < OUT_DIM) bfcs[t] = bfc[t];
    __syncthreads();

    int n = (blockIdx.x * 256 + t) >> 6;
    int lane = t & 63;
    if (n >= N) return;

    float dn = dinv[n];
    float acc = dn * dn * h[(size_t)n * HID + lane];

    int beg = rowptr[n], end = rowptr[n + 1];
    int j = beg;
    for (; j + 7 < end; j += 8) {
        int2 p0 = edges[j];
        int2 p1 = edges[j + 1];
        int2 p2 = edges[j + 2];
        int2 p3 = edges[j + 3];
        int2 p4 = edges[j + 4];
        int2 p5 = edges[j + 5];
        int2 p6 = edges[j + 6];
        int2 p7 = edges[j + 7];
        float h0 = bf2f(hb[(size_t)p0.x * HID + lane]);
        float h1 = bf2f(hb[(size_t)p1.x * HID + lane]);
        float h2v = bf2f(hb[(size_t)p2.x * HID + lane]);
        float h3 = bf2f(hb[(size_t)p3.x * HID + lane]);
        float h4 = bf2f(hb[(size_t)p4.x * HID + lane]);
        float h5 = bf2f(hb[(size_t)p5.x * HID + lane]);
        float h6 = bf2f(hb[(size_t)p6.x * HID + lane]);
        float h7 = bf2f(hb[(size_t)p7.x * HID + lane]);
        acc = fmaf(__int_as_float(p0.y), h0, acc);
        acc = fmaf(__int_as_float(p1.y), h1, acc);
        acc = fmaf(__int_as_float(p2.y), h2v, acc);
        acc = fmaf(__int_as_float(p3.y), h3, acc);
        acc = fmaf(__int_as_float(p4.y), h4, acc);
        acc = fmaf(__int_as_float(p5.y), h5, acc);
        acc = fmaf(__int_as_float(p6.y), h6, acc);
        acc = fmaf(__int_as_float(p7.y), h7, acc);
    }
    for (; j < end; ++j) {
        int2 p = edges[j];
        acc = fmaf(__int_as_float(p.y), bf2f(hb[(size_t)p.x * HID + lane]), acc);
    }

    float f = fmaxf(acc + b2s[lane], 0.f);
    float vo[OUT_DIM];
#pragma unroll
    for (int o = 0; o < OUT_DIM; ++o) {
        float v = f * Wfs[lane * OUT_DIM + o];
#pragma unroll
        for (int off = 32; off >= 1; off >>= 1)
            v += __shfl_xor(v, off, 64);
        vo[o] = v;
    }
    if (lane == 0) {
#pragma unroll
        for (int o = 0; o < OUT_DIM; ++o)
            out[(size_t)n * OUT_DIM + o] = vo[o] + bfcs[o];
    }
}

// ---------------- host launch ----------------

static inline size_t align_up(size_t x, size_t a) { return (x + a - 1) & ~(a - 1); }

extern "C" void kernel_launch(void* const* d_in, const int* in_sizes, int n_in,
                              void* d_out, int out_size, void* d_ws, size_t ws_size,
                              hipStream_t stream) {
    const float* x   = (const float*)d_in[0];
    const int*   ei  = (const int*)d_in[1];   // [2][E] int32
    const float* ew  = (const float*)d_in[2];
    const float* W1  = (const float*)d_in[3];
    const float* b1  = (const float*)d_in[4];
    const float* W2  = (const float*)d_in[5];
    const float* b2  = (const float*)d_in[6];
    const float* Wfc = (const float*)d_in[7];
    const float* bfc = (const float*)d_in[8];
    float* out = (float*)d_out;

    const int E = in_sizes[2];              // 3200000
    const int N = in_sizes[0] / IN_DIM;     // 100000
    const int* src = ei;
    const int* dst = ei + E;

    // workspace carve. Aliasing: rank and hb2 share one 12.8 MB slot —
    // rank is read last by k_reorder; hb2 is first written by k_agg_gemm2
    // (strictly later, same stream). hb1 is a real buffer (GEMM1 writes it
    // concurrently with hist writing rank).
    char* p = (char*)d_ws;
    unsigned long long* packed = (unsigned long long*)p; p += align_up((size_t)N * 8, 256);
    float* dinv   = (float*)p;  p += align_up((size_t)N * 4, 256);
    int*   rowptr = (int*)p;    p += align_up((size_t)(N + 1) * 4, 256);
    int*   bsum   = (int*)p;    p += align_up((size_t)256 * 4, 256);
    unsigned short* hb1 = (unsigned short*)p; p += align_up((size_t)N * HID * 2, 256); // 12.8 MB
    int2*  edges  = (int2*)p;   p += align_up((size_t)E * 8, 256);   // 25.6 MB
    float* bufA   = (float*)p;  p += align_up((size_t)N * HID * 4, 256); // 25.6 MB
    float* bufB   = (float*)p;  p += align_up((size_t)N * HID * 4, 256); // 25.6 MB
    int*   rank   = (int*)p;    // 12.8 MB slot shared:
    unsigned short* hb2 = (unsigned short*)p;
    p += align_up((size_t)E * 4, 256);
    (void)ws_size; (void)n_in; (void)out_size;

    const int BS = 256;
    dim3 blk(BS);
    int gN  = (N + BS - 1) / BS;
    int gN1 = (N + 1 + BS - 1) / BS;
    int gE  = (E + BS - 1) / BS;
    int gE4 = (E + BS * 4 - 1) / (BS * 4);
    int gM  = (N + 63) / 64;
    int nb  = (N + 1023) / 1024;
    int gAg = (N + 3) / 4;

    // CSR build overlapped with GEMM1 (independent inputs)
    k_init<<<gN, blk, 0, stream>>>(packed, N);
    k_gemm1_hist<<<gM + gE4, blk, 0, stream>>>(x, W1, bufA, hb1, N,
                                               dst, ew, packed, rank, E, gM);
    k_scan1d<<<nb, blk, 0, stream>>>(packed, dinv, rowptr, bsum, N);
    k_scan2<<<1, blk, 0, stream>>>(bsum, nb);
    k_scan3<<<gN1, blk, 0, stream>>>(rowptr, bsum, N, E);
    k_reorder<<<gE, blk, 0, stream>>>(src, dst, ew, dinv, rowptr, rank, edges, E);

    // layer 1 aggregate + layer 2 transform (rank dead -> hb2 reuses its slot)
    k_agg_gemm2<<<gAg, blk, 0, stream>>>(bufA, hb1, dinv, edges, rowptr,
                                         b1, W2, bufB, hb2, N);

    // layer 2 aggregate + final FC
    k_agg_final<<<gAg, blk, 0, stream>>>(bufB, hb2, dinv, edges, rowptr,
                                         b2, Wfc, bfc, out, N);
}

// Round 11
// 758.935 us; speedup vs baseline: 1.0964x; 1.0501x over previous
//
#include <hip/hip_runtime.h>

#define IN_DIM 512
#define HID 64
#define OUT_DIM 5

// ---------------- bf16 helpers (RNE) ----------------

__device__ __forceinline__ unsigned short f2bf(float f) {
    unsigned u = __float_as_uint(f);
    u += 0x7FFF + ((u >> 16) & 1);
    return (unsigned short)(u >> 16);
}
__device__ __forceinline__ float bf2f(unsigned short b) {
    return __uint_as_float(((unsigned)b) << 16);
}

// ---------------- init: packed deg/count accumulator = 0 ----------------

__global__ void k_init(unsigned long long* __restrict__ packed, int n) {
    int i = blockIdx.x * blockDim.x + threadIdx.x;
    if (i < n) packed[i] = 0ULL;
}

// ---------------- fused GEMM1 + hist ----------------
// GEMM1 (x @ W1) is independent of the CSR build; hist is bound by the fabric
// atomic transaction rate (~22 G atomics/s — insensitive to concurrency (r4),
// per-line spreading (r7), NT hints (r8) -> structural). Block-split fusion
// hides GEMM1 under the atomic wait.

__launch_bounds__(256)
__global__ void k_gemm1_hist(const float* __restrict__ A, const float* __restrict__ W,
                             float* __restrict__ out, unsigned short* __restrict__ outb, int M,
                             const int* __restrict__ dst, const float* __restrict__ ew,
                             unsigned long long* __restrict__ packed, int* __restrict__ rank,
                             int nE, int gemmBlocks) {
    if ((int)blockIdx.x < gemmBlocks) {
        constexpr int K_ = IN_DIM;
        constexpr int BK = 16;
        __shared__ float As[BK][68];
        __shared__ float Ws[BK][64];

        const int t  = threadIdx.x;
        const int tx = t & 15;
        const int ty = t >> 4;
        const int row0 = blockIdx.x * 64;

        const int lr = t >> 2;
        const int lk = (t & 3) * 4;

        float acc[4][4] = {};

        for (int k0 = 0; k0 < K_; k0 += BK) {
            float4 av = make_float4(0.f, 0.f, 0.f, 0.f);
            int ar = row0 + lr;
            if (ar < M) av = *(const float4*)&A[(long long)ar * K_ + k0 + lk];
            As[lk + 0][lr] = av.x;
            As[lk + 1][lr] = av.y;
            As[lk + 2][lr] = av.z;
            As[lk + 3][lr] = av.w;

            *(float4*)&Ws[t >> 4][(t & 15) * 4] =
                *(const float4*)&W[(long long)(k0 + (t >> 4)) * 64 + (t & 15) * 4];

            __syncthreads();

#pragma unroll
            for (int kk = 0; kk < BK; ++kk) {
                float4 a4 = *(const float4*)&As[kk][ty * 4];
                float4 b4 = *(const float4*)&Ws[kk][tx * 4];
                float a[4] = {a4.x, a4.y, a4.z, a4.w};
                float b[4] = {b4.x, b4.y, b4.z, b4.w};
#pragma unroll
                for (int i = 0; i < 4; ++i)
#pragma unroll
                    for (int j = 0; j < 4; ++j)
                        acc[i][j] = fmaf(a[i], b[j], acc[i][j]);
            }
            __syncthreads();
        }

#pragma unroll
        for (int i = 0; i < 4; ++i) {
            int r = row0 + ty * 4 + i;
            if (r < M) {
                *(float4*)&out[(long long)r * 64 + tx * 4] =
                    make_float4(acc[i][0], acc[i][1], acc[i][2], acc[i][3]);
                ushort4 hv;
                hv.x = f2bf(acc[i][0]);
                hv.y = f2bf(acc[i][1]);
                hv.z = f2bf(acc[i][2]);
                hv.w = f2bf(acc[i][3]);
                *(ushort4*)&outb[(long long)r * 64 + tx * 4] = hv;
            }
        }
    } else {
        int base = ((blockIdx.x - gemmBlocks) * 256 + threadIdx.x) * 4;
        if (base + 3 < nE) {
            int4   d4 = *(const int4*)&dst[base];
            float4 w4 = *(const float4*)&ew[base];
            unsigned long long f0 = (unsigned long long)(w4.x * 4294967296.0);
            unsigned long long f1 = (unsigned long long)(w4.y * 4294967296.0);
            unsigned long long f2 = (unsigned long long)(w4.z * 4294967296.0);
            unsigned long long f3 = (unsigned long long)(w4.w * 4294967296.0);
            unsigned long long o0 = atomicAdd(&packed[d4.x], (1ULL << 44) | f0);
            unsigned long long o1 = atomicAdd(&packed[d4.y], (1ULL << 44) | f1);
            unsigned long long o2 = atomicAdd(&packed[d4.z], (1ULL << 44) | f2);
            unsigned long long o3 = atomicAdd(&packed[d4.w], (1ULL << 44) | f3);
            int4 r4;
            r4.x = (int)(o0 >> 44);
            r4.y = (int)(o1 >> 44);
            r4.z = (int)(o2 >> 44);
            r4.w = (int)(o3 >> 44);
            *(int4*)&rank[base] = r4;
        } else {
            for (int e = base; e < nE; ++e) {
                int d = dst[e];
                unsigned long long fx = (unsigned long long)(ew[e] * 4294967296.0);
                unsigned long long old = atomicAdd(&packed[d], (1ULL << 44) | fx);
                rank[e] = (int)(old >> 44);
            }
        }
    }
}

// ---------------- scan1 + dinv fused: reads packed directly ----------------

__global__ void k_scan1d(const unsigned long long* __restrict__ packed,
                         float* __restrict__ dinv, int* __restrict__ rowptr,
                         int* __restrict__ bsum, int n) {
    __shared__ int sdata[256];
    int t = threadIdx.x, b = blockIdx.x;
    int base = b * 1024 + t * 4;
    int v[4], s = 0;
#pragma unroll
    for (int k = 0; k < 4; ++k) {
        int i = base + k;
        int c = 0;
        if (i < n) {
            unsigned long long p = packed[i];
            c = (int)(p >> 44);
            double ewsum = (double)(p & ((1ULL << 44) - 1)) * (1.0 / 4294967296.0);
            dinv[i] = rsqrtf(1.0f + (float)ewsum);
        }
        v[k] = c;
        s += c;
    }
    sdata[t] = s;
    __syncthreads();
    int x = s;
    for (int off = 1; off < 256; off <<= 1) {
        int y = (t >= off) ? sdata[t - off] : 0;
        __syncthreads();
        x += y;
        sdata[t] = x;
        __syncthreads();
    }
    int run = x - s;
    if (t == 255) bsum[b] = x;
#pragma unroll
    for (int k = 0; k < 4; ++k) { int i = base + k; if (i < n) rowptr[i] = run; run += v[k]; }
}

__global__ void k_scan2(int* __restrict__ bsum, int nb) {
    __shared__ int sdata[256];
    int t = threadIdx.x;
    int s = (t < nb) ? bsum[t] : 0;
    sdata[t] = s;
    __syncthreads();
    int x = s;
    for (int off = 1; off < 256; off <<= 1) {
        int y = (t >= off) ? sdata[t - off] : 0;
        __syncthreads();
        x += y;
        sdata[t] = x;
        __syncthreads();
    }
    if (t < nb) bsum[t] = x - s;
}

__global__ void k_scan3(int* __restrict__ rowptr, const int* __restrict__ bsum, int n, int E) {
    int i = blockIdx.x * blockDim.x + threadIdx.x;
    if (i < n) rowptr[i] += bsum[i >> 10];
    else if (i == n) rowptr[n] = E;
}

// ---------------- reorder: NO atomics — pos = rowptr[dst] + rank ----------------

__global__ void k_reorder(const int* __restrict__ src, const int* __restrict__ dst,
                          const float* __restrict__ ew, const float* __restrict__ dinv,
                          const int* __restrict__ rowptr, const int* __restrict__ rank,
                          int2* __restrict__ edges, int nE) {
    int e = blockIdx.x * blockDim.x + threadIdx.x;
    if (e < nE) {
        int s = src[e];
        int d = dst[e];
        float w = dinv[s] * ew[e] * dinv[d];
        int pos = rowptr[d] + rank[e];
        edges[pos] = make_int2(s, __float_as_int(w));
    }
}

// ---------------- aggregate: out[n,:] = dinv[n]^2*h[n,:] + sum_e w_e * hb[src_e,:] ----
// one wave per node, lane = feature. hb row = 128 B = one cache line, fully
// consumed per wave-gather. Measured ~2.4 TB/s of L3-line gather traffic ->
// near the Infinity-Cache scattered-fetch ceiling; in-wave GEMM epilogue
// fusion (r10) did NOT hide under this — it serialized (+49 us). Keep plain.

__launch_bounds__(256)
__global__ void k_aggregate(const float* __restrict__ h, const unsigned short* __restrict__ hb,
                            const float* __restrict__ dinv,
                            const int2* __restrict__ edges, const int* __restrict__ rowptr,
                            float* __restrict__ out, int N) {
    int n = (blockIdx.x * 256 + threadIdx.x) >> 6;
    int lane = threadIdx.x & 63;
    if (n >= N) return;

    float dn = dinv[n];
    float acc = dn * dn * h[(size_t)n * HID + lane];

    int beg = rowptr[n], end = rowptr[n + 1];
    int j = beg;
    for (; j + 7 < end; j += 8) {
        int2 p0 = edges[j];
        int2 p1 = edges[j + 1];
        int2 p2 = edges[j + 2];
        int2 p3 = edges[j + 3];
        int2 p4 = edges[j + 4];
        int2 p5 = edges[j + 5];
        int2 p6 = edges[j + 6];
        int2 p7 = edges[j + 7];
        float h0 = bf2f(hb[(size_t)p0.x * HID + lane]);
        float h1 = bf2f(hb[(size_t)p1.x * HID + lane]);
        float h2 = bf2f(hb[(size_t)p2.x * HID + lane]);
        float h3 = bf2f(hb[(size_t)p3.x * HID + lane]);
        float h4 = bf2f(hb[(size_t)p4.x * HID + lane]);
        float h5 = bf2f(hb[(size_t)p5.x * HID + lane]);
        float h6 = bf2f(hb[(size_t)p6.x * HID + lane]);
        float h7 = bf2f(hb[(size_t)p7.x * HID + lane]);
        acc = fmaf(__int_as_float(p0.y), h0, acc);
        acc = fmaf(__int_as_float(p1.y), h1, acc);
        acc = fmaf(__int_as_float(p2.y), h2, acc);
        acc = fmaf(__int_as_float(p3.y), h3, acc);
        acc = fmaf(__int_as_float(p4.y), h4, acc);
        acc = fmaf(__int_as_float(p5.y), h5, acc);
        acc = fmaf(__int_as_float(p6.y), h6, acc);
        acc = fmaf(__int_as_float(p7.y), h7, acc);
    }
    for (; j < end; ++j) {
        int2 p = edges[j];
        acc = fmaf(__int_as_float(p.y), bf2f(hb[(size_t)p.x * HID + lane]), acc);
    }
    out[(size_t)n * HID + lane] = acc;
}

// ---------------- tiled GEMM: out[M,64] = act(A[M,K]) @ W[K,64]; also bf16 copy ----------------

template <int K_, bool RELU_BIAS>
__launch_bounds__(256)
__global__ void k_gemm_n64(const float* __restrict__ A, const float* __restrict__ W,
                           const float* __restrict__ bias, float* __restrict__ out,
                           unsigned short* __restrict__ outb, int M) {
    constexpr int BK = 16;
    __shared__ float As[BK][68];
    __shared__ float Ws[BK][64];

    const int t  = threadIdx.x;
    const int tx = t & 15;
    const int ty = t >> 4;
    const int row0 = blockIdx.x * 64;

    const int lr = t >> 2;
    const int lk = (t & 3) * 4;

    float acc[4][4] = {};

    for (int k0 = 0; k0 < K_; k0 += BK) {
        float4 av = make_float4(0.f, 0.f, 0.f, 0.f);
        int ar = row0 + lr;
        if (ar < M) {
            av = *(const float4*)&A[(long long)ar * K_ + k0 + lk];
            if (RELU_BIAS) {
                const float4 bv = *(const float4*)&bias[k0 + lk];
                av.x = fmaxf(av.x + bv.x, 0.f);
                av.y = fmaxf(av.y + bv.y, 0.f);
                av.z = fmaxf(av.z + bv.z, 0.f);
                av.w = fmaxf(av.w + bv.w, 0.f);
            }
        }
        As[lk + 0][lr] = av.x;
        As[lk + 1][lr] = av.y;
        As[lk + 2][lr] = av.z;
        As[lk + 3][lr] = av.w;

        *(float4*)&Ws[t >> 4][(t & 15) * 4] =
            *(const float4*)&W[(long long)(k0 + (t >> 4)) * 64 + (t & 15) * 4];

        __syncthreads();

#pragma unroll
        for (int kk = 0; kk < BK; ++kk) {
            float4 a4 = *(const float4*)&As[kk][ty * 4];
            float4 b4 = *(const float4*)&Ws[kk][tx * 4];
            float a[4] = {a4.x, a4.y, a4.z, a4.w};
            float b[4] = {b4.x, b4.y, b4.z, b4.w};
#pragma unroll
            for (int i = 0; i < 4; ++i)
#pragma unroll
                for (int j = 0; j < 4; ++j)
                    acc[i][j] = fmaf(a[i], b[j], acc[i][j]);
        }
        __syncthreads();
    }

#pragma unroll
    for (int i = 0; i < 4; ++i) {
        int r = row0 + ty * 4 + i;
        if (r < M) {
            *(float4*)&out[(long long)r * 64 + tx * 4] =
                make_float4(acc[i][0], acc[i][1], acc[i][2], acc[i][3]);
            ushort4 hv;
            hv.x = f2bf(acc[i][0]);
            hv.y = f2bf(acc[i][1]);
            hv.z = f2bf(acc[i][2]);
            hv.w = f2bf(acc[i][3]);
            *(ushort4*)&outb[(long long)r * 64 + tx * 4] = hv;
        }
    }
}

// ---------------- fused aggregate2 + final FC ----------------
// Wave per node: aggregate layer 2, then f = relu(acc + b2[lane]) and
// out[n][o] = butterfly_sum(f * Wfc[lane][o]) + bfc[o]. Epilogue is only
// 30 shfl (vs r10's 64-shfl GEMM that serialized) — kills k_final + a
// 25.6 MB bufB round-trip.

__launch_bounds__(256)
__global__ void k_agg_final(const float* __restrict__ h, const unsigned short* __restrict__ hb,
                            const float* __restrict__ dinv,
                            const int2* __restrict__ edges, const int* __restrict__ rowptr,
                            const float* __restrict__ b2, const float* __restrict__ Wfc,
                            const float* __restrict__ bfc, float* __restrict__ out, int N) {
    __shared__ float Wfs[HID * OUT_DIM];
    __shared__ float b2s[HID];
    __shared__ float bfcs[OUT_DIM];
    const int t = threadIdx.x;
    for (int i = t; i < HID * OUT_DIM; i += 256) Wfs[i] = Wfc[i];
    if (t < HID) b2s[t] = b2[t];
    if (t < OUT_DIM) bfcs[t] = bfc[t];
    __syncthreads();

    int n = (blockIdx.x * 256 + t) >> 6;
    int lane = t & 63;
    if (n >= N) return;

    float dn = dinv[n];
    float acc = dn * dn * h[(size_t)n * HID + lane];

    int beg = rowptr[n], end = rowptr[n + 1];
    int j = beg;
    for (; j + 7 < end; j += 8) {
        int2 p0 = edges[j];
        int2 p1 = edges[j + 1];
        int2 p2 = edges[j + 2];
        int2 p3 = edges[j + 3];
        int2 p4 = edges[j + 4];
        int2 p5 = edges[j + 5];
        int2 p6 = edges[j + 6];
        int2 p7 = edges[j + 7];
        float h0 = bf2f(hb[(size_t)p0.x * HID + lane]);
        float h1 = bf2f(hb[(size_t)p1.x * HID + lane]);
        float h2v = bf2f(hb[(size_t)p2.x * HID + lane]);
        float h3 = bf2f(hb[(size_t)p3.x * HID + lane]);
        float h4 = bf2f(hb[(size_t)p4.x * HID + lane]);
        float h5 = bf2f(hb[(size_t)p5.x * HID + lane]);
        float h6 = bf2f(hb[(size_t)p6.x * HID + lane]);
        float h7 = bf2f(hb[(size_t)p7.x * HID + lane]);
        acc = fmaf(__int_as_float(p0.y), h0, acc);
        acc = fmaf(__int_as_float(p1.y), h1, acc);
        acc = fmaf(__int_as_float(p2.y), h2v, acc);
        acc = fmaf(__int_as_float(p3.y), h3, acc);
        acc = fmaf(__int_as_float(p4.y), h4, acc);
        acc = fmaf(__int_as_float(p5.y), h5, acc);
        acc = fmaf(__int_as_float(p6.y), h6, acc);
        acc = fmaf(__int_as_float(p7.y), h7, acc);
    }
    for (; j < end; ++j) {
        int2 p = edges[j];
        acc = fmaf(__int_as_float(p.y), bf2f(hb[(size_t)p.x * HID + lane]), acc);
    }

    float f = fmaxf(acc + b2s[lane], 0.f);
    float vo[OUT_DIM];
#pragma unroll
    for (int o = 0; o < OUT_DIM; ++o) {
        float v = f * Wfs[lane * OUT_DIM + o];
#pragma unroll
        for (int off = 32; off >= 1; off >>= 1)
            v += __shfl_xor(v, off, 64);
        vo[o] = v;
    }
    if (lane == 0) {
#pragma unroll
        for (int o = 0; o < OUT_DIM; ++o)
            out[(size_t)n * OUT_DIM + o] = vo[o] + bfcs[o];
    }
}

// ---------------- host launch ----------------

static inline size_t align_up(size_t x, size_t a) { return (x + a - 1) & ~(a - 1); }

extern "C" void kernel_launch(void* const* d_in, const int* in_sizes, int n_in,
                              void* d_out, int out_size, void* d_ws, size_t ws_size,
                              hipStream_t stream) {
    const float* x   = (const float*)d_in[0];
    const int*   ei  = (const int*)d_in[1];   // [2][E] int32
    const float* ew  = (const float*)d_in[2];
    const float* W1  = (const float*)d_in[3];
    const float* b1  = (const float*)d_in[4];
    const float* W2  = (const float*)d_in[5];
    const float* b2  = (const float*)d_in[6];
    const float* Wfc = (const float*)d_in[7];
    const float* bfc = (const float*)d_in[8];
    float* out = (float*)d_out;

    const int E = in_sizes[2];              // 3200000
    const int N = in_sizes[0] / IN_DIM;     // 100000
    const int* src = ei;
    const int* dst = ei + E;

    // workspace carve (r6 scheme). rank aliases bufB: rank read last by
    // k_reorder; bufB first written by k_aggregate (strictly later, same
    // stream). hb is real (GEMM1 writes it while hist writes rank); gemm2
    // overwrites hb AFTER agg1 finished reading layer-1 values (sequential).
    char* p = (char*)d_ws;
    unsigned long long* packed = (unsigned long long*)p; p += align_up((size_t)N * 8, 256);
    float* dinv   = (float*)p;  p += align_up((size_t)N * 4, 256);
    int*   rowptr = (int*)p;    p += align_up((size_t)(N + 1) * 4, 256);
    int*   bsum   = (int*)p;    p += align_up((size_t)256 * 4, 256);
    unsigned short* hb = (unsigned short*)p; p += align_up((size_t)N * HID * 2, 256); // 12.8 MB
    int2*  edges  = (int2*)p;   p += align_up((size_t)E * 8, 256);   // 25.6 MB
    float* bufA   = (float*)p;  p += align_up((size_t)N * HID * 4, 256);
    float* bufB   = (float*)p;  p += align_up((size_t)N * HID * 4, 256);
    int*   rank   = (int*)bufB;  // E*4 = 12.8 MB <= bufB's 25.6 MB
    (void)ws_size; (void)n_in; (void)out_size;

    const int BS = 256;
    dim3 blk(BS);
    int gN  = (N + BS - 1) / BS;
    int gN1 = (N + 1 + BS - 1) / BS;
    int gE  = (E + BS - 1) / BS;
    int gE4 = (E + BS * 4 - 1) / (BS * 4);
    int gM  = (N + 63) / 64;
    int nb  = (N + 1023) / 1024;
    int gAg = (N + 3) / 4;

    // CSR build overlapped with GEMM1 (independent inputs)
    k_init<<<gN, blk, 0, stream>>>(packed, N);
    k_gemm1_hist<<<gM + gE4, blk, 0, stream>>>(x, W1, bufA, hb, N,
                                               dst, ew, packed, rank, E, gM);
    k_scan1d<<<nb, blk, 0, stream>>>(packed, dinv, rowptr, bsum, N);
    k_scan2<<<1, blk, 0, stream>>>(bsum, nb);
    k_scan3<<<gN1, blk, 0, stream>>>(rowptr, bsum, N, E);
    k_reorder<<<gE, blk, 0, stream>>>(src, dst, ew, dinv, rowptr, rank, edges, E);

    // layer 1 aggregate (writes bufB — rank dead from here on)
    k_aggregate<<<gAg, blk, 0, stream>>>(bufA, hb, dinv, edges, rowptr, bufB, N);

    // layer 2 transform (separate — r10 proved in-wave GEMM fusion serializes)
    k_gemm_n64<HID, true><<<gM, blk, 0, stream>>>(bufB, W2, b1, bufA, hb, N);

    // layer 2 aggregate + final FC (cheap epilogue; kills k_final + round-trip)
    k_agg_final<<<gAg, blk, 0, stream>>>(bufA, hb, dinv, edges, rowptr,
                                         b2, Wfc, bfc, out, N);
}